// Round 1
// baseline (4424.219 us; speedup 1.0000x reference)
//
#include <hip/hip_runtime.h>

#define HH 384
#define WW 384
#define BB 64
#define NC 3
#define KS 16
#define HOUT 24
#define WOUT 24
#define NP 576        // HOUT*WOUT
#define EMB 768
#define PLEN 768      // NC*KS*KS
#define LOC 8         // locations per block

__global__ __launch_bounds__(256)
void deform_patch_kernel(const float* __restrict__ pix,
                         const float* __restrict__ offw,
                         const float* __restrict__ offb,
                         const float* __restrict__ projw,
                         const float* __restrict__ projb,
                         float* __restrict__ out) {
    __shared__ float buf[LOC][PLEN];   // patches, then reused for sampled values
    const int tid = threadIdx.x;
    const int loc0 = blockIdx.x * LOC;

    // ---------------- Phase A: stage 8 patches into LDS (float4 loads) ----
    // 8 loc * 768 floats = 1536 float4 items; 6 per thread.
    #pragma unroll
    for (int r = 0; r < 6; ++r) {
        int item = tid + r * 256;          // 0..1535
        int l    = item / 192;             // which loc
        int k4   = item - l * 192;         // float4 index within patch
        int k    = k4 * 4;                 // k = c*256 + i*16 + j
        int c    = k >> 8;
        int i    = (k >> 4) & 15;
        int j    = k & 15;
        int flat = loc0 + l;
        int b  = flat / NP;
        int p  = flat - b * NP;
        int ho = p / WOUT;
        int wo = p - ho * WOUT;
        const float4 v = *(const float4*)(pix +
            (((size_t)b * NC + c) * HH + (size_t)ho * KS + i) * WW + wo * KS + j);
        *(float4*)(&buf[l][k]) = v;
    }
    __syncthreads();

    // ---------------- Phase B: offset conv. thread t -> (dy,dx) of ij=t ---
    float dy[LOC], dx[LOC];
    {
        float acc0[LOC], acc1[LOC];
        const float b0 = offb[2 * tid];
        const float b1 = offb[2 * tid + 1];
        #pragma unroll
        for (int l = 0; l < LOC; ++l) { acc0[l] = b0; acc1[l] = b1; }
        const float4* w0 = (const float4*)(offw + (size_t)(2 * tid) * PLEN);
        const float4* w1 = w0 + PLEN / 4;
        for (int k4 = 0; k4 < PLEN / 4; ++k4) {
            float4 wa = w0[k4];
            float4 wb = w1[k4];
            #pragma unroll
            for (int l = 0; l < LOC; ++l) {
                float4 pv = *(const float4*)(&buf[l][k4 * 4]);   // LDS broadcast
                acc0[l] += wa.x * pv.x + wa.y * pv.y + wa.z * pv.z + wa.w * pv.w;
                acc1[l] += wb.x * pv.x + wb.y * pv.y + wb.z * pv.z + wb.w * pv.w;
            }
        }
        #pragma unroll
        for (int l = 0; l < LOC; ++l) { dy[l] = acc0[l]; dx[l] = acc1[l]; }
    }
    __syncthreads();   // everyone done reading patches

    // ---------------- Phase C: bilinear gather; thread t handles ij=t -----
    {
        const int i = tid >> 4;
        const int j = tid & 15;
        #pragma unroll
        for (int l = 0; l < LOC; ++l) {
            int flat = loc0 + l;
            int b  = flat / NP;
            int p  = flat - b * NP;
            int ho = p / WOUT;
            int wo = p - ho * WOUT;
            float py = (float)(ho * KS + i) + dy[l];
            float px = (float)(wo * KS + j) + dx[l];
            float y0 = floorf(py), x0 = floorf(px);
            float wy1 = py - y0, wy0 = 1.f - wy1;
            float wx1 = px - x0, wx0 = 1.f - wx1;
            const float* pb = pix + (size_t)b * NC * HH * WW;
            float s0 = 0.f, s1 = 0.f, s2 = 0.f;
            #pragma unroll
            for (int cy = 0; cy < 2; ++cy) {
                #pragma unroll
                for (int cx = 0; cx < 2; ++cx) {
                    float yf = y0 + (float)cy;
                    float xf = x0 + (float)cx;
                    float w = (cy ? wy1 : wy0) * (cx ? wx1 : wx0);
                    bool valid = (yf >= 0.f) && (yf < (float)HH) &&
                                 (xf >= 0.f) && (xf < (float)WW);
                    if (valid) {
                        int yi = (int)yf;
                        int xi = (int)xf;
                        int idx = yi * WW + xi;
                        s0 += w * pb[idx];
                        s1 += w * pb[HH * WW + idx];
                        s2 += w * pb[2 * HH * WW + idx];
                    }
                }
            }
            buf[l][tid]       = s0;   // k = 0*256 + ij
            buf[l][256 + tid] = s1;   // k = 1*256 + ij
            buf[l][512 + tid] = s2;   // k = 2*256 + ij
        }
    }
    __syncthreads();

    // ---------------- Phase D: projection. thread t -> outputs t,t+256,t+512
    {
        float accA[LOC], accB[LOC], accC[LOC];
        const float bA = projb[tid];
        const float bB = projb[tid + 256];
        const float bC = projb[tid + 512];
        #pragma unroll
        for (int l = 0; l < LOC; ++l) { accA[l] = bA; accB[l] = bB; accC[l] = bC; }
        const float4* wA = (const float4*)(projw + (size_t)tid * PLEN);
        const float4* wB = (const float4*)(projw + (size_t)(tid + 256) * PLEN);
        const float4* wC = (const float4*)(projw + (size_t)(tid + 512) * PLEN);
        for (int k4 = 0; k4 < PLEN / 4; ++k4) {
            float4 a = wA[k4];
            float4 bq = wB[k4];
            float4 cq = wC[k4];
            #pragma unroll
            for (int l = 0; l < LOC; ++l) {
                float4 pv = *(const float4*)(&buf[l][k4 * 4]);   // LDS broadcast
                accA[l] += a.x * pv.x + a.y * pv.y + a.z * pv.z + a.w * pv.w;
                accB[l] += bq.x * pv.x + bq.y * pv.y + bq.z * pv.z + bq.w * pv.w;
                accC[l] += cq.x * pv.x + cq.y * pv.y + cq.z * pv.z + cq.w * pv.w;
            }
        }
        #pragma unroll
        for (int l = 0; l < LOC; ++l) {
            int flat = loc0 + l;
            float* op = out + (size_t)flat * EMB;
            op[tid]       = accA[l];
            op[tid + 256] = accB[l];
            op[tid + 512] = accC[l];
        }
    }
}

extern "C" void kernel_launch(void* const* d_in, const int* in_sizes, int n_in,
                              void* d_out, int out_size, void* d_ws, size_t ws_size,
                              hipStream_t stream) {
    const float* pix   = (const float*)d_in[0];
    const float* offw  = (const float*)d_in[1];
    const float* offb  = (const float*)d_in[2];
    const float* projw = (const float*)d_in[3];
    const float* projb = (const float*)d_in[4];
    float* out = (float*)d_out;

    const int nloc = BB * NP;              // 36864
    dim3 grid(nloc / LOC);                 // 4608 blocks
    deform_patch_kernel<<<grid, 256, 0, stream>>>(pix, offw, offb, projw, projb, out);
}

// Round 2
// 302.187 us; speedup vs baseline: 14.6407x; 14.6407x over previous
//
#include <hip/hip_runtime.h>
#include <stdint.h>

typedef __bf16 bf16x8 __attribute__((ext_vector_type(8)));
typedef float  f32x4  __attribute__((ext_vector_type(4)));

#define HH 384
#define WW 384
#define NPIX (HH*WW)
#define NC 3
#define NPATCH 576
#define EMB 768
#define PLEN 768
#define MLOC 32
#define KSTEPS 24
#define NLOC (64*576)
#define W1_UNITS (32*24*64)      /* 49152 16B-units for offset weights  */
#define W2_UNITS (48*24*64)      /* 73728 16B-units for proj weights    */
#define W2_OFF   (W1_UNITS*8)    /* element offset of w2 inside ws      */

__device__ __forceinline__ uint16_t f2bf(float f) {
    uint32_t u = __builtin_bit_cast(uint32_t, f);
    u += 0x7FFFu + ((u >> 16) & 1u);
    return (uint16_t)(u >> 16);
}
__device__ __forceinline__ uint32_t pk2(float a, float b) {
    return (uint32_t)f2bf(a) | ((uint32_t)f2bf(b) << 16);
}

// Pre-convert both weight matrices to bf16 in MFMA-fragment order:
// unit u -> (nt, ks, lane); elems: n = nt*16 + (lane&15), k = ks*32 + (lane>>4)*8 + e
__global__ __launch_bounds__(256)
void convert_weights(const float* __restrict__ offw, const float* __restrict__ projw,
                     uint16_t* __restrict__ wz) {
    int u = blockIdx.x * 256 + threadIdx.x;
    const float* src;
    int uu;
    if (u < W1_UNITS) { src = offw; uu = u; }
    else              { src = projw; uu = u - W1_UNITS; }
    int lane = uu & 63;
    int t    = uu >> 6;
    int ks   = t % KSTEPS;
    int nt   = t / KSTEPS;
    int n    = nt * 16 + (lane & 15);
    int k0   = ks * 32 + (lane >> 4) * 8;
    const float4* s4 = (const float4*)(src + (size_t)n * PLEN + k0);
    float4 v0 = s4[0], v1 = s4[1];
    uint4 w;
    w.x = pk2(v0.x, v0.y); w.y = pk2(v0.z, v0.w);
    w.z = pk2(v1.x, v1.y); w.w = pk2(v1.z, v1.w);
    *(uint4*)(wz + (size_t)u * 8) = w;
}

template<bool USE_WS>
__global__ __launch_bounds__(256, 2)
void fused_kernel(const float* __restrict__ pix,
                  const float* __restrict__ offw,
                  const float* __restrict__ offb,
                  const float* __restrict__ projw,
                  const float* __restrict__ projb,
                  const uint16_t* __restrict__ wz,
                  float* __restrict__ out) {
    // A-matrix LDS: bf16 [32 loc][768 k], XOR-swizzled (16B units across 8 rows)
    __shared__ __align__(16) uint16_t As[MLOC][PLEN];

    const int tid  = threadIdx.x;
    const int wv   = tid >> 6;
    const int lane = tid & 63;
    const int lr   = lane & 15;     // row/col-in-tile selector
    const int lg   = lane >> 4;     // k-group selector
    const int loc0 = blockIdx.x * MLOC;
    const int bimg = loc0 / NPATCH;            // uniform per block
    const int p0   = loc0 - bimg * NPATCH;     // uniform per block
    const float* __restrict__ pb = pix + (size_t)bimg * NC * NPIX;

    // ---------------- Phase A: stage 32 patches (f32 -> bf16, swizzled) ----
    #pragma unroll
    for (int uu = 0; uu < 12; ++uu) {
        int unit = tid + uu * 256;             // 0..3071 (32 loc x 96 units)
        int loc  = unit / 96;
        int k8   = (unit - loc * 96) * 8;      // element index, 8-aligned
        int c  = k8 >> 8;
        int i  = (k8 >> 4) & 15;
        int j  = k8 & 15;
        int p  = p0 + loc;
        int ho = p / 24;
        int wo = p - ho * 24;
        const float* g = pb + ((size_t)c * HH + ho * 16 + i) * WW + wo * 16 + j;
        float4 v0 = *(const float4*)g;
        float4 v1 = *(const float4*)(g + 4);
        uint4 w;
        w.x = pk2(v0.x, v0.y); w.y = pk2(v0.z, v0.w);
        w.z = pk2(v1.x, v1.y); w.w = pk2(v1.z, v1.w);
        *(uint4*)&As[loc][k8 ^ ((loc & 7) << 3)] = w;
    }
    __syncthreads();

    // ---------------- GEMM1: offsets [32 x 512] = A[32x768] * W1^T ---------
    f32x4 acc1[2][8];
    #pragma unroll
    for (int nt = 0; nt < 8; ++nt) {
        float bz = offb[(wv * 8 + nt) * 16 + lr];
        f32x4 z = {bz, bz, bz, bz};
        acc1[0][nt] = z; acc1[1][nt] = z;
    }
    {
        const int sw0 = (lr & 7) << 3;   // rows lr and 16+lr share (row&7)
        #pragma unroll 1
        for (int ks = 0; ks < KSTEPS; ++ks) {
            int ke = (ks * 32 + lg * 8) ^ sw0;
            bf16x8 a0 = *(const bf16x8*)&As[lr][ke];
            bf16x8 a1 = *(const bf16x8*)&As[16 + lr][ke];
            #pragma unroll
            for (int nt = 0; nt < 8; ++nt) {
                bf16x8 bfr;
                if (USE_WS) {
                    bfr = *(const bf16x8*)(wz + ((size_t)(((wv*8+nt) * KSTEPS + ks) * 64 + lane)) * 8);
                } else {
                    int n = (wv*8+nt) * 16 + lr;
                    const float4* s4 = (const float4*)(offw + (size_t)n * PLEN + ks*32 + lg*8);
                    float4 v0 = s4[0], v1 = s4[1];
                    uint4 uq = {pk2(v0.x,v0.y), pk2(v0.z,v0.w), pk2(v1.x,v1.y), pk2(v1.z,v1.w)};
                    bfr = __builtin_bit_cast(bf16x8, uq);
                }
                acc1[0][nt] = __builtin_amdgcn_mfma_f32_16x16x32_bf16(a0, bfr, acc1[0][nt], 0, 0, 0);
                acc1[1][nt] = __builtin_amdgcn_mfma_f32_16x16x32_bf16(a1, bfr, acc1[1][nt], 0, 0, 0);
            }
        }
    }
    __syncthreads();   // patch A-matrix dead; LDS reused for sampled values

    // ---------------- Pair (dy,dx) in-register via shfl_xor ----------------
    // D layout: col n = tile*16 + lr, row m = lg*4 + r. Channel n=2q is dy(q),
    // n=2q+1 is dx(q); adjacent lanes hold the pair. Even lanes keep n-tiles
    // 0..3, odd lanes 4..7 -> no duplicated gathers.
    const int even = ((lane & 1) == 0);
    float dyg[4][2][4], dxg[4][2][4];
    #pragma unroll
    for (int nt = 0; nt < 8; ++nt)
      #pragma unroll
      for (int mt = 0; mt < 2; ++mt)
        #pragma unroll
        for (int r = 0; r < 4; ++r) {
            float v  = acc1[mt][nt][r];
            float pv = __shfl_xor(v, 1);
            if ((nt < 4) == (even != 0)) {
                int s = nt & 3;
                dyg[s][mt][r] = even ? v  : pv;
                dxg[s][mt][r] = even ? pv : v;
            }
        }

    // ---------------- Phase C: bilinear gather -> bf16 sampled into LDS ----
    const int ntb  = wv * 8 + (even ? 0 : 4);
    const int qlow = lr >> 1;
    #pragma unroll
    for (int s = 0; s < 4; ++s) {
        int q  = (ntb + s) * 8 + qlow;   // patch pixel 0..255
        int qi = q >> 4;
        int qj = q & 15;
        #pragma unroll
        for (int mt = 0; mt < 2; ++mt)
          #pragma unroll
          for (int r = 0; r < 4; ++r) {
            int locl = mt * 16 + lg * 4 + r;
            int p  = p0 + locl;
            int ho = p / 24;
            int wo = p - ho * 24;
            float py = (float)(ho * 16 + qi) + dyg[s][mt][r];
            float px = (float)(wo * 16 + qj) + dxg[s][mt][r];
            float y0f = floorf(py), x0f = floorf(px);
            float wy1 = py - y0f, wy0 = 1.f - wy1;
            float wx1 = px - x0f, wx0 = 1.f - wx1;
            int y0 = (int)y0f, x0 = (int)x0f;
            float s0 = 0.f, s1 = 0.f, s2 = 0.f;
            #pragma unroll
            for (int cy = 0; cy < 2; ++cy) {
                int yy = y0 + cy;
                if ((unsigned)yy < (unsigned)HH) {
                    float wy = cy ? wy1 : wy0;
                    #pragma unroll
                    for (int cx = 0; cx < 2; ++cx) {
                        int xx = x0 + cx;
                        if ((unsigned)xx < (unsigned)WW) {
                            float w = wy * (cx ? wx1 : wx0);
                            const float* cp = pb + yy * WW + xx;
                            s0 += w * cp[0];
                            s1 += w * cp[NPIX];
                            s2 += w * cp[2 * NPIX];
                        }
                    }
                }
            }
            int swl = (locl & 7) << 3;
            As[locl][(      q) ^ swl] = f2bf(s0);
            As[locl][(256 + q) ^ swl] = f2bf(s1);
            As[locl][(512 + q) ^ swl] = f2bf(s2);
          }
    }
    __syncthreads();

    // ---------------- GEMM2: out [32 x 768] = S[32x768] * W2^T -------------
    f32x4 acc2[2][12];
    #pragma unroll
    for (int nt = 0; nt < 12; ++nt) {
        float bz = projb[(wv * 12 + nt) * 16 + lr];
        f32x4 z = {bz, bz, bz, bz};
        acc2[0][nt] = z; acc2[1][nt] = z;
    }
    {
        const int sw0 = (lr & 7) << 3;
        const uint16_t* __restrict__ w2 = wz + W2_OFF;
        #pragma unroll 1
        for (int ks = 0; ks < KSTEPS; ++ks) {
            int ke = (ks * 32 + lg * 8) ^ sw0;
            bf16x8 a0 = *(const bf16x8*)&As[lr][ke];
            bf16x8 a1 = *(const bf16x8*)&As[16 + lr][ke];
            #pragma unroll
            for (int nt = 0; nt < 12; ++nt) {
                bf16x8 bfr;
                if (USE_WS) {
                    bfr = *(const bf16x8*)(w2 + ((size_t)(((wv*12+nt) * KSTEPS + ks) * 64 + lane)) * 8);
                } else {
                    int n = (wv*12+nt) * 16 + lr;
                    const float4* s4 = (const float4*)(projw + (size_t)n * PLEN + ks*32 + lg*8);
                    float4 v0 = s4[0], v1 = s4[1];
                    uint4 uq = {pk2(v0.x,v0.y), pk2(v0.z,v0.w), pk2(v1.x,v1.y), pk2(v1.z,v1.w)};
                    bfr = __builtin_bit_cast(bf16x8, uq);
                }
                acc2[0][nt] = __builtin_amdgcn_mfma_f32_16x16x32_bf16(a0, bfr, acc2[0][nt], 0, 0, 0);
                acc2[1][nt] = __builtin_amdgcn_mfma_f32_16x16x32_bf16(a1, bfr, acc2[1][nt], 0, 0, 0);
            }
        }
    }

    // ---------------- Epilogue: direct f32 stores --------------------------
    #pragma unroll
    for (int mt = 0; mt < 2; ++mt)
      #pragma unroll
      for (int r = 0; r < 4; ++r) {
        int flat = loc0 + mt * 16 + lg * 4 + r;
        float* op = out + (size_t)flat * EMB;
        #pragma unroll
        for (int nt = 0; nt < 12; ++nt)
            op[(wv * 12 + nt) * 16 + lr] = acc2[mt][nt][r];
      }
}

extern "C" void kernel_launch(void* const* d_in, const int* in_sizes, int n_in,
                              void* d_out, int out_size, void* d_ws, size_t ws_size,
                              hipStream_t stream) {
    const float* pix   = (const float*)d_in[0];
    const float* offw  = (const float*)d_in[1];
    const float* offb  = (const float*)d_in[2];
    const float* projw = (const float*)d_in[3];
    const float* projb = (const float*)d_in[4];
    float* out = (float*)d_out;
    uint16_t* wz = (uint16_t*)d_ws;

    const size_t ws_needed = (size_t)(W1_UNITS + W2_UNITS) * 16;  // bytes
    dim3 grid(NLOC / MLOC);   // 1152

    if (ws_size >= ws_needed) {
        convert_weights<<<(W1_UNITS + W2_UNITS) / 256, 256, 0, stream>>>(offw, projw, wz);
        fused_kernel<true><<<grid, 256, 0, stream>>>(pix, offw, offb, projw, projb, wz, out);
    } else {
        fused_kernel<false><<<grid, 256, 0, stream>>>(pix, offw, offb, projw, projb, wz, out);
    }
}

// Round 3
// 206.252 us; speedup vs baseline: 21.4506x; 1.4651x over previous
//
#include <hip/hip_runtime.h>
#include <stdint.h>

typedef __bf16 bf16x8 __attribute__((ext_vector_type(8)));
typedef float  f32x4  __attribute__((ext_vector_type(4)));

#define HH 384
#define WW 384
#define NPIX (HH*WW)
#define NC 3
#define NPATCH 576
#define EMB 768
#define PLEN 768
#define MLOC 32
#define KSTEPS 24
#define NLOC (64*576)
#define NT1 4                    /* GEMM1 n-tiles per wave (8 waves x 4 = 32) */
#define NT2 6                    /* GEMM2 n-tiles per wave (8 waves x 6 = 48) */
#define W1_UNITS (32*KSTEPS*64)  /* 16B-units for offset weights */
#define W2_UNITS (48*KSTEPS*64)  /* 16B-units for proj weights   */
#define W2_OFF   (W1_UNITS*8)

__device__ __forceinline__ uint16_t f2bf(float f) {
    uint32_t u = __builtin_bit_cast(uint32_t, f);
    u += 0x7FFFu + ((u >> 16) & 1u);
    return (uint16_t)(u >> 16);
}
__device__ __forceinline__ uint32_t pk2(float a, float b) {
    return (uint32_t)f2bf(a) | ((uint32_t)f2bf(b) << 16);
}

// Pre-convert both weight matrices to bf16 in MFMA-fragment order:
// unit u -> (nt, ks, lane); n = nt*16 + (lane&15), k = ks*32 + (lane>>4)*8 + e
__global__ __launch_bounds__(256)
void convert_weights(const float* __restrict__ offw, const float* __restrict__ projw,
                     uint16_t* __restrict__ wz) {
    int u = blockIdx.x * 256 + threadIdx.x;
    const float* src;
    int uu;
    if (u < W1_UNITS) { src = offw; uu = u; }
    else              { src = projw; uu = u - W1_UNITS; }
    int lane = uu & 63;
    int t    = uu >> 6;
    int ks   = t % KSTEPS;
    int nt   = t / KSTEPS;
    int n    = nt * 16 + (lane & 15);
    int k0   = ks * 32 + (lane >> 4) * 8;
    const float4* s4 = (const float4*)(src + (size_t)n * PLEN + k0);
    float4 v0 = s4[0], v1 = s4[1];
    uint4 w;
    w.x = pk2(v0.x, v0.y); w.y = pk2(v0.z, v0.w);
    w.z = pk2(v1.x, v1.y); w.w = pk2(v1.z, v1.w);
    *(uint4*)(wz + (size_t)u * 8) = w;
}

template<bool USE_WS>
__global__ __launch_bounds__(512, 4)
void fused_kernel(const float* __restrict__ pix,
                  const float* __restrict__ offw,
                  const float* __restrict__ offb,
                  const float* __restrict__ projw,
                  const float* __restrict__ projb,
                  const uint16_t* __restrict__ wz,
                  float* __restrict__ out) {
    __shared__ __align__(16) uint16_t As[MLOC][PLEN];   // 48 KB, XOR-swizzled rows

    const int tid  = threadIdx.x;
    const int wv   = tid >> 6;
    const int lane = tid & 63;
    const int lr   = lane & 15;
    const int lg   = lane >> 4;

    // bijective XCD swizzle: 1152 blocks = 8 XCDs x 144
    int bid = (int)blockIdx.x;
    bid = (bid & 7) * 144 + (bid >> 3);

    const int loc0 = bid * MLOC;
    const int bimg = loc0 / NPATCH;
    const int p0   = loc0 - bimg * NPATCH;
    const float* __restrict__ pb = pix + (size_t)bimg * NC * NPIX;

    // ---------------- Phase A: stage 32 patches (f32 -> bf16, swizzled) ----
    #pragma unroll
    for (int uu = 0; uu < 6; ++uu) {
        int unit = tid + uu * 512;             // 0..3071
        int loc  = unit / 96;
        int k8   = (unit - loc * 96) * 8;
        int c  = k8 >> 8;
        int i  = (k8 >> 4) & 15;
        int j  = k8 & 15;
        int p  = p0 + loc;
        int ho = p / 24;
        int wo = p - ho * 24;
        const float* g = pb + ((size_t)c * HH + ho * 16 + i) * WW + wo * 16 + j;
        float4 v0 = *(const float4*)g;
        float4 v1 = *(const float4*)(g + 4);
        uint4 w;
        w.x = pk2(v0.x, v0.y); w.y = pk2(v0.z, v0.w);
        w.z = pk2(v1.x, v1.y); w.w = pk2(v1.z, v1.w);
        *(uint4*)&As[loc][k8 ^ ((loc & 7) << 3)] = w;
    }

    const int sw0 = (lr & 7) << 3;

    // ---------------- GEMM1: offsets [32 x 512], B double-buffered ---------
    auto ldb1 = [&](int ntg, int ks) -> bf16x8 {
        if (USE_WS) {
            return *(const bf16x8*)(wz + ((size_t)((ntg * KSTEPS + ks) * 64 + lane)) * 8);
        } else {
            int n = ntg * 16 + lr;
            const float4* s4 = (const float4*)(offw + (size_t)n * PLEN + ks * 32 + lg * 8);
            float4 v0 = s4[0], v1 = s4[1];
            uint4 uq = {pk2(v0.x,v0.y), pk2(v0.z,v0.w), pk2(v1.x,v1.y), pk2(v1.z,v1.w)};
            return __builtin_bit_cast(bf16x8, uq);
        }
    };
    bf16x8 b1a[NT1], b1b[NT1];
    #pragma unroll
    for (int nt = 0; nt < NT1; ++nt) b1a[nt] = ldb1(wv * NT1 + nt, 0);  // pre-barrier prefetch
    __syncthreads();

    f32x4 acc1[2][NT1];
    #pragma unroll
    for (int nt = 0; nt < NT1; ++nt) {
        float bz = offb[(wv * NT1 + nt) * 16 + lr];
        f32x4 z = {bz, bz, bz, bz};
        acc1[0][nt] = z; acc1[1][nt] = z;
    }
    #pragma unroll 1
    for (int ks2 = 0; ks2 < KSTEPS / 2; ++ks2) {
        const int ks0 = ks2 * 2;
        {   // even step: consume b1a, prefetch b1b @ ks0+1
            #pragma unroll
            for (int nt = 0; nt < NT1; ++nt) b1b[nt] = ldb1(wv * NT1 + nt, ks0 + 1);
            int ke = (ks0 * 32 + lg * 8) ^ sw0;
            bf16x8 a0 = *(const bf16x8*)&As[lr][ke];
            bf16x8 a1 = *(const bf16x8*)&As[16 + lr][ke];
            __builtin_amdgcn_s_setprio(1);
            #pragma unroll
            for (int nt = 0; nt < NT1; ++nt) {
                acc1[0][nt] = __builtin_amdgcn_mfma_f32_16x16x32_bf16(a0, b1a[nt], acc1[0][nt], 0, 0, 0);
                acc1[1][nt] = __builtin_amdgcn_mfma_f32_16x16x32_bf16(a1, b1a[nt], acc1[1][nt], 0, 0, 0);
            }
            __builtin_amdgcn_s_setprio(0);
        }
        {   // odd step: consume b1b, prefetch b1a @ ks0+2
            int ksn = (ks0 + 2 < KSTEPS) ? ks0 + 2 : 0;
            #pragma unroll
            for (int nt = 0; nt < NT1; ++nt) b1a[nt] = ldb1(wv * NT1 + nt, ksn);
            int ke = ((ks0 + 1) * 32 + lg * 8) ^ sw0;
            bf16x8 a0 = *(const bf16x8*)&As[lr][ke];
            bf16x8 a1 = *(const bf16x8*)&As[16 + lr][ke];
            __builtin_amdgcn_s_setprio(1);
            #pragma unroll
            for (int nt = 0; nt < NT1; ++nt) {
                acc1[0][nt] = __builtin_amdgcn_mfma_f32_16x16x32_bf16(a0, b1b[nt], acc1[0][nt], 0, 0, 0);
                acc1[1][nt] = __builtin_amdgcn_mfma_f32_16x16x32_bf16(a1, b1b[nt], acc1[1][nt], 0, 0, 0);
            }
            __builtin_amdgcn_s_setprio(0);
        }
    }
    __syncthreads();   // all waves done reading patch A-matrix

    // ---------------- Pair (dy,dx) in-register via shfl_xor ----------------
    // D layout: col n = (wv*NT1+nt)*16 + lr, row = lg*4+r (+16 per mt).
    // n=2q is dy(q), n=2q+1 is dx(q). Even lanes keep local tiles {0,1},
    // odd lanes {2,3} -> each lane owns 2 tiles, s in {0,1}.
    const int even = ((lane & 1) == 0);
    float dyg[2][2][4], dxg[2][2][4];
    #pragma unroll
    for (int nt = 0; nt < NT1; ++nt)
      #pragma unroll
      for (int mt = 0; mt < 2; ++mt)
        #pragma unroll
        for (int r = 0; r < 4; ++r) {
            float v  = acc1[mt][nt][r];
            float pv = __shfl_xor(v, 1);
            if ((nt < 2) == (even != 0)) {
                int s = nt & 1;
                dyg[s][mt][r] = even ? v  : pv;
                dxg[s][mt][r] = even ? pv : v;
            }
        }

    // ---------------- Phase C: bilinear gather -> bf16 sampled into LDS ----
    const int ntb  = wv * NT1 + (even ? 0 : 2);
    const int qlow = lr >> 1;
    #pragma unroll
    for (int s = 0; s < 2; ++s) {
        int q  = (ntb + s) * 8 + qlow;   // patch pixel 0..255
        int qi = q >> 4;
        int qj = q & 15;
        #pragma unroll
        for (int mt = 0; mt < 2; ++mt)
          #pragma unroll
          for (int r = 0; r < 4; ++r) {
            int locl = mt * 16 + lg * 4 + r;
            int p  = p0 + locl;
            int ho = p / 24;
            int wo = p - ho * 24;
            float py = (float)(ho * 16 + qi) + dyg[s][mt][r];
            float px = (float)(wo * 16 + qj) + dxg[s][mt][r];
            float y0f = floorf(py), x0f = floorf(px);
            float wy1 = py - y0f, wy0 = 1.f - wy1;
            float wx1 = px - x0f, wx0 = 1.f - wx1;
            int y0 = (int)y0f, x0 = (int)x0f;
            float s0 = 0.f, s1 = 0.f, s2 = 0.f;
            #pragma unroll
            for (int cy = 0; cy < 2; ++cy) {
                int yy = y0 + cy;
                if ((unsigned)yy < (unsigned)HH) {
                    float wy = cy ? wy1 : wy0;
                    #pragma unroll
                    for (int cx = 0; cx < 2; ++cx) {
                        int xx = x0 + cx;
                        if ((unsigned)xx < (unsigned)WW) {
                            float w = wy * (cx ? wx1 : wx0);
                            const float* cp = pb + yy * WW + xx;
                            s0 += w * cp[0];
                            s1 += w * cp[NPIX];
                            s2 += w * cp[2 * NPIX];
                        }
                    }
                }
            }
            int swl = (locl & 7) << 3;
            As[locl][(      q) ^ swl] = f2bf(s0);
            As[locl][(256 + q) ^ swl] = f2bf(s1);
            As[locl][(512 + q) ^ swl] = f2bf(s2);
          }
    }

    // ---------------- GEMM2: out [32 x 768], B double-buffered -------------
    auto ldb2 = [&](int ntg, int ks) -> bf16x8 {
        if (USE_WS) {
            return *(const bf16x8*)(wz + W2_OFF + ((size_t)((ntg * KSTEPS + ks) * 64 + lane)) * 8);
        } else {
            int n = ntg * 16 + lr;
            const float4* s4 = (const float4*)(projw + (size_t)n * PLEN + ks * 32 + lg * 8);
            float4 v0 = s4[0], v1 = s4[1];
            uint4 uq = {pk2(v0.x,v0.y), pk2(v0.z,v0.w), pk2(v1.x,v1.y), pk2(v1.z,v1.w)};
            return __builtin_bit_cast(bf16x8, uq);
        }
    };
    bf16x8 b2a[NT2], b2b[NT2];
    #pragma unroll
    for (int nt = 0; nt < NT2; ++nt) b2a[nt] = ldb2(wv * NT2 + nt, 0);  // pre-barrier prefetch
    __syncthreads();

    f32x4 acc2[2][NT2];
    #pragma unroll
    for (int nt = 0; nt < NT2; ++nt) {
        float bz = projb[(wv * NT2 + nt) * 16 + lr];
        f32x4 z = {bz, bz, bz, bz};
        acc2[0][nt] = z; acc2[1][nt] = z;
    }
    #pragma unroll 1
    for (int ks2 = 0; ks2 < KSTEPS / 2; ++ks2) {
        const int ks0 = ks2 * 2;
        {
            #pragma unroll
            for (int nt = 0; nt < NT2; ++nt) b2b[nt] = ldb2(wv * NT2 + nt, ks0 + 1);
            int ke = (ks0 * 32 + lg * 8) ^ sw0;
            bf16x8 a0 = *(const bf16x8*)&As[lr][ke];
            bf16x8 a1 = *(const bf16x8*)&As[16 + lr][ke];
            __builtin_amdgcn_s_setprio(1);
            #pragma unroll
            for (int nt = 0; nt < NT2; ++nt) {
                acc2[0][nt] = __builtin_amdgcn_mfma_f32_16x16x32_bf16(a0, b2a[nt], acc2[0][nt], 0, 0, 0);
                acc2[1][nt] = __builtin_amdgcn_mfma_f32_16x16x32_bf16(a1, b2a[nt], acc2[1][nt], 0, 0, 0);
            }
            __builtin_amdgcn_s_setprio(0);
        }
        {
            int ksn = (ks0 + 2 < KSTEPS) ? ks0 + 2 : 0;
            #pragma unroll
            for (int nt = 0; nt < NT2; ++nt) b2a[nt] = ldb2(wv * NT2 + nt, ksn);
            int ke = ((ks0 + 1) * 32 + lg * 8) ^ sw0;
            bf16x8 a0 = *(const bf16x8*)&As[lr][ke];
            bf16x8 a1 = *(const bf16x8*)&As[16 + lr][ke];
            __builtin_amdgcn_s_setprio(1);
            #pragma unroll
            for (int nt = 0; nt < NT2; ++nt) {
                acc2[0][nt] = __builtin_amdgcn_mfma_f32_16x16x32_bf16(a0, b2b[nt], acc2[0][nt], 0, 0, 0);
                acc2[1][nt] = __builtin_amdgcn_mfma_f32_16x16x32_bf16(a1, b2b[nt], acc2[1][nt], 0, 0, 0);
            }
            __builtin_amdgcn_s_setprio(0);
        }
    }

    // ---------------- Epilogue: direct f32 stores --------------------------
    #pragma unroll
    for (int mt = 0; mt < 2; ++mt)
      #pragma unroll
      for (int r = 0; r < 4; ++r) {
        int flat = loc0 + mt * 16 + lg * 4 + r;
        float* op = out + (size_t)flat * EMB;
        #pragma unroll
        for (int nt = 0; nt < NT2; ++nt)
            op[(wv * NT2 + nt) * 16 + lr] = acc2[mt][nt][r];
      }
}

extern "C" void kernel_launch(void* const* d_in, const int* in_sizes, int n_in,
                              void* d_out, int out_size, void* d_ws, size_t ws_size,
                              hipStream_t stream) {
    const float* pix   = (const float*)d_in[0];
    const float* offw  = (const float*)d_in[1];
    const float* offb  = (const float*)d_in[2];
    const float* projw = (const float*)d_in[3];
    const float* projb = (const float*)d_in[4];
    float* out = (float*)d_out;
    uint16_t* wz = (uint16_t*)d_ws;

    const size_t ws_needed = (size_t)(W1_UNITS + W2_UNITS) * 16;  // ~1.97 MB
    dim3 grid(NLOC / MLOC);   // 1152

    if (ws_size >= ws_needed) {
        convert_weights<<<(W1_UNITS + W2_UNITS) / 256, 256, 0, stream>>>(offw, projw, wz);
        fused_kernel<true><<<grid, 512, 0, stream>>>(pix, offw, offb, projw, projb, wz, out);
    } else {
        fused_kernel<false><<<grid, 512, 0, stream>>>(pix, offw, offb, projw, projb, wz, out);
    }
}